// Round 7
// baseline (681.753 us; speedup 1.0000x reference)
//
#include <hip/hip_runtime.h>
#include <cmath>

#define NB 4
#define NC 128
#define NH 128
#define NW 128
#define HD 64
#define WD 64
#define NL 4096      // 64*64 positions / patches
#define NPIX 16384   // 128*128 output pixels per batch
#define SM_SCALE 2550.0f
#define CUT 40.0f
#define CUTS 0.216f  // candidate margin in score units
#define MAXENT 8
#define MAXC 256
#define PLMAX 32     // 4 positions x MAXENT survivors

struct Ent { int l; float p; };

typedef __attribute__((ext_vector_type(4))) float f32x4;
typedef __attribute__((ext_vector_type(8))) short s16x8;

__device__ __forceinline__ unsigned short f2bf(float x) {
  unsigned u = __float_as_uint(x);
  return (unsigned short)((u + 0x7fffu + ((u >> 16) & 1u)) >> 16);
}
__device__ __forceinline__ float bf2f(unsigned short h) {
  return __uint_as_float(((unsigned)h) << 16);
}
__device__ __forceinline__ unsigned fenc(float v) {   // order-preserving float->uint
  unsigned b = __float_as_uint(v);
  return (b >> 31) ? ~b : (b | 0x80000000u);
}
__device__ __forceinline__ float fdec(unsigned e) {
  unsigned b = (e >> 31) ? (e ^ 0x80000000u) : ~e;    // e==0 -> NaN (no candidates)
  return __uint_as_float(b);
}
__device__ __forceinline__ void gload_lds16(const void* g, void* l) {
  __builtin_amdgcn_global_load_lds(
      (const __attribute__((address_space(1))) void*)g,
      (__attribute__((address_space(3))) void*)l, 16, 0, 0);
}

// ---------- prep ----------
__global__ void k_prep(const float* __restrict__ f, const float* __restrict__ b,
                       float* __restrict__ fd, float* __restrict__ bd) {
  int i = blockIdx.x * blockDim.x + threadIdx.x;
  if (i >= NB*NC*HD*WD) return;
  int x = i & 63, y = (i >> 6) & 63, c = (i >> 12) & 127, bb = i >> 19;
  int src = ((bb*NC + c)*NH + 2*y)*NW + 2*x;
  fd[i] = f[src];
  bd[i] = b[src];
}

__global__ void k_sq(const float* __restrict__ bd, double* __restrict__ sq) {
  int i = blockIdx.x * blockDim.x + threadIdx.x;
  if (i >= NB*HD*WD) return;
  int x = i & 63, y = (i >> 6) & 63, bb = i >> 12;
  double s = 0.0;
  const float* p = bd + (size_t)bb*NC*HD*WD + y*WD + x;
  for (int c = 0; c < NC; ++c) {
    double v = (double)p[(size_t)c*HD*WD];
    s += v*v;
  }
  sq[i] = s;
}

__global__ void k_normmm(const double* __restrict__ sq, const float* __restrict__ mask,
                         float* __restrict__ norm, float* __restrict__ mmv,
                         int* __restrict__ zb) {
  int i = blockIdx.x * blockDim.x + threadIdx.x;
  if (i >= NB*NL) return;
  int pw = i & 63, ph = (i >> 6) & 63, bb = i >> 12;
  double s = 0.0;
  for (int dh = -1; dh <= 1; ++dh) {
    int y = ph + dh; if ((unsigned)y >= 64u) continue;
    for (int dw = -1; dw <= 1; ++dw) {
      int x = pw + dw; if ((unsigned)x >= 64u) continue;
      s += sq[(bb*HD + y)*WD + x];
    }
  }
  norm[i] = (float)sqrt(s);
  float ms = 0.f;
  const float* mb = mask + (size_t)bb*512*512;
  for (int dh = -1; dh <= 1; ++dh) {
    int y = ph + dh; if ((unsigned)y >= 64u) continue;
    for (int dw = -1; dw <= 1; ++dw) {
      int x = pw + dw; if ((unsigned)x >= 64u) continue;
      ms += mb[(y*8)*512 + x*8];
    }
  }
  float m = (ms == 0.f) ? 1.f : 0.f;
  mmv[i] = m;
  if (m == 0.f) atomicAdd(&zb[bb], 1);
}

// ---------- transpose b to pixel-major b_t[bb][pix][c] (for gather) ----------
__global__ __launch_bounds__(256) void k_btrans(const float* __restrict__ b,
                                                float* __restrict__ bt) {
  __shared__ float tile[32][33];
  int bb = blockIdx.z;
  int c0 = blockIdx.y * 32;
  int p0 = blockIdx.x * 32;
  int tx = threadIdx.x & 31, ty = threadIdx.x >> 5;
  const float* bp = b + (size_t)bb*NC*NPIX;
  #pragma unroll
  for (int r = 0; r < 32; r += 8)
    tile[r + ty][tx] = bp[(size_t)(c0 + r + ty)*NPIX + p0 + tx];
  __syncthreads();
  float* btp = bt + (size_t)bb*NPIX*NC;
  #pragma unroll
  for (int r = 0; r < 32; r += 8)
    btp[(size_t)(p0 + r + ty)*NC + c0 + tx] = tile[tx][r + ty];
}

// ---------- transpose fd,bd to pixel-major bf16 (GEMM-D operands) ----------
__global__ __launch_bounds__(256) void k_fbtrans(const float* __restrict__ fd,
    const float* __restrict__ bd, unsigned short* __restrict__ fdt,
    unsigned short* __restrict__ bdt) {
  __shared__ float tf[32][33], tb[32][33];
  int bb = blockIdx.z;
  int c0 = blockIdx.y * 32;
  int p0 = blockIdx.x * 32;
  int tx = threadIdx.x & 31, ty = threadIdx.x >> 5;
  const float* fp = fd + (size_t)bb*NC*NL;
  const float* bp = bd + (size_t)bb*NC*NL;
  #pragma unroll
  for (int r = 0; r < 32; r += 8) {
    tf[r + ty][tx] = fp[(size_t)(c0 + r + ty)*NL + p0 + tx];
    tb[r + ty][tx] = bp[(size_t)(c0 + r + ty)*NL + p0 + tx];
  }
  __syncthreads();
  #pragma unroll
  for (int r = 0; r < 32; r += 8) {
    fdt[((size_t)bb*NL + p0 + r + ty)*NC + c0 + tx] = f2bf(tf[tx][r + ty]);
    bdt[((size_t)bb*NL + p0 + r + ty)*NC + c0 + tx] = f2bf(tb[tx][r + ty]);
  }
}

// ---------- pixel-dot GEMM, K=128; D stored in diag-pair layout ----------
// D_dp[((py*64 + ly)*64 + px)*64 + lx] = <fd_pix(py,px), bd_pix(ly,lx)>
__global__ __launch_bounds__(256) void k_gemmD(
    const unsigned short* __restrict__ A, const unsigned short* __restrict__ B,
    unsigned short* __restrict__ D) {
  __shared__ __align__(16) unsigned short As[128*32];
  __shared__ __align__(16) unsigned short Bs[128*32];
  int t = threadIdx.x;
  int w = t >> 6, l = t & 63;
  int by = blockIdx.y, bx = blockIdx.x;
  int wr = w >> 1, wc = w & 1;
  f32x4 acc[4][4] = {};
  int aoff[4], boff[4];
  #pragma unroll
  for (int m = 0; m < 4; ++m) {
    aoff[m] = ((wr*64 + m*16 + (l & 15)) * 32 + ((l >> 4) * 8)) * 2;
    boff[m] = ((wc*64 + m*16 + (l & 15)) * 32 + ((l >> 4) * 8)) * 2;
  }
  const char* Ab = (const char*)A;
  const char* Bb = (const char*)B;
  char* AsB = (char*)As;
  char* BsB = (char*)Bs;
  int off = (w*2) * 1024 + l * 16;
  int r0 = off >> 6, cb0 = off & 63;
  int off1 = off + 1024;
  int r1 = off1 >> 6, cb1 = off1 & 63;
  for (int k0 = 0; k0 < 128; k0 += 32) {
    gload_lds16(Ab + ((size_t)(by*128 + r0) * 128 + k0) * 2 + cb0, AsB + (w*2+0)*1024);
    gload_lds16(Ab + ((size_t)(by*128 + r1) * 128 + k0) * 2 + cb1, AsB + (w*2+1)*1024);
    gload_lds16(Bb + ((size_t)(bx*128 + r0) * 128 + k0) * 2 + cb0, BsB + (w*2+0)*1024);
    gload_lds16(Bb + ((size_t)(bx*128 + r1) * 128 + k0) * 2 + cb1, BsB + (w*2+1)*1024);
    __syncthreads();
    s16x8 af[4], bf[4];
    #pragma unroll
    for (int m = 0; m < 4; ++m) af[m] = *(const s16x8*)(AsB + aoff[m]);
    #pragma unroll
    for (int n = 0; n < 4; ++n) bf[n] = *(const s16x8*)(BsB + boff[n]);
    #pragma unroll
    for (int m = 0; m < 4; ++m)
      #pragma unroll
      for (int n = 0; n < 4; ++n)
        acc[m][n] = __builtin_amdgcn_mfma_f32_16x16x32_bf16(af[m], bf[n], acc[m][n], 0, 0, 0);
    __syncthreads();
  }
  int cr = l >> 4;
  int cc = l & 15;
  #pragma unroll
  for (int n = 0; n < 4; ++n) {
    int col = bx*128 + wc*64 + n*16 + cc;     // global l
    int ly = col >> 6, lx = col & 63;
    #pragma unroll
    for (int m = 0; m < 4; ++m) {
      int grow = by*128 + wr*64 + m*16 + cr*4;  // global p
      #pragma unroll
      for (int j = 0; j < 4; ++j) {
        int gp = grow + j;
        size_t addr = ((size_t)((gp >> 6)*64 + ly)*64 + (gp & 63))*64 + lx;
        D[addr] = f2bf(acc[m][n][j]);
      }
    }
  }
}

// ---------- diag-pair stencil: block = (py,ly), 3 tiles in LDS ----------
// S[py,px][ly,lx] = sum_{dh,dw} D_dp[py+dh][ly+dh][px+dw][lx+dw]
__global__ __launch_bounds__(256) void k_stencil2(const unsigned short* __restrict__ D,
    const float* __restrict__ nrm, const float* __restrict__ mmv,
    unsigned short* __restrict__ Sb, unsigned* __restrict__ rowmax, int bb) {
  __shared__ __align__(16) unsigned short Dl[3*4096];   // 24 KB
  __shared__ unsigned rmx_s[64];
  int t = threadIdx.x;
  int w = t >> 6, lane = t & 63;
  // diagonal ordering + XCD chunking: each XCD walks 8 full diagonals
  int orig = (blockIdx.x & 7) * 512 + (blockIdx.x >> 3);
  int dgn = orig >> 6, s = orig & 63;
  int ly = s, py = (dgn + s) & 63;

  bool val[3];
  #pragma unroll
  for (int dh = -1; dh <= 1; ++dh) {
    int idx = dh + 1;
    int pyq = py + dh, lyq = ly + dh;
    val[idx] = ((unsigned)pyq < 64u) && ((unsigned)lyq < 64u);
    if (val[idx]) {
      const char* src = (const char*)(D + (size_t)(pyq*64 + lyq)*4096);
      char* dst = (char*)Dl + idx*8192;
      gload_lds16(src + w*1024 + lane*16, dst + w*1024);
      gload_lds16(src + 4096 + w*1024 + lane*16, dst + 4096 + w*1024);
    }
  }
  if (t < 64) rmx_s[t] = 0u;
  __syncthreads();

  int lxb = (t*2) & 63;
  float rn0 = 1.f / fmaxf(nrm[bb*NL + ly*64 + lxb], 1e-4f);
  float rn1 = 1.f / fmaxf(nrm[bb*NL + ly*64 + lxb + 1], 1e-4f);
  float m0 = mmv[bb*NL + ly*64 + lxb];
  float m1 = mmv[bb*NL + ly*64 + lxb + 1];

  float sv[8][2] = {};
  #pragma unroll
  for (int dh = -1; dh <= 1; ++dh) {
    if (!val[dh+1]) continue;
    const unsigned short* tile = Dl + (dh+1)*4096;
    #pragma unroll
    for (int dw = -1; dw <= 1; ++dw) {
      #pragma unroll
      for (int j = 0; j < 8; ++j) {
        int base = j*512 + t*2;
        int px = base >> 6;
        if ((unsigned)(px + dw) >= 64u) continue;
        #pragma unroll
        for (int i = 0; i < 2; ++i) {
          if ((unsigned)(lxb + i + dw) < 64u)
            sv[j][i] += bf2f(tile[base + i + dw*65]);
        }
      }
    }
  }

  #pragma unroll
  for (int j = 0; j < 8; ++j) {
    int px = (j*512 + t*2) >> 6;
    unsigned short s0 = f2bf(sv[j][0] * rn0);
    unsigned short s1 = f2bf(sv[j][1] * rn1);
    unsigned pack = (unsigned)s0 | ((unsigned)s1 << 16);
    *(unsigned*)(Sb + (size_t)(py*64 + px)*4096 + ly*64 + lxb) = pack;
    if (m0 != 0.f) atomicMax(&rmx_s[px], fenc(bf2f(s0)));
    if (m1 != 0.f) atomicMax(&rmx_s[px], fenc(bf2f(s1)));
  }
  __syncthreads();
  if (t < 64) atomicMax(&rowmax[py*64 + t], rmx_s[t]);
}

// ---------- fused scan + exact rescore (round-3 verified) ----------
__global__ __launch_bounds__(256) void k_rescore2(const unsigned short* __restrict__ Sb,
    const float* __restrict__ mmv, const unsigned* __restrict__ rowmax,
    const float* __restrict__ fd, const float* __restrict__ bd,
    const float* __restrict__ nrm, const int* __restrict__ zb,
    int* __restrict__ cnt, Ent* __restrict__ ent, float* __restrict__ ooff, int bb) {
  int p = blockIdx.x, t = threadIdx.x;
  int wid = t >> 6, lane = t & 63;
  int ihp = p >> 6, iwp = p & 63;
  __shared__ float fpat[1152];
  __shared__ int cl[MAXC];
  __shared__ float cs[MAXC];
  __shared__ int cnt_s;
  if (t == 0) cnt_s = 0;
  const float* fdb = fd + (size_t)bb*NC*HD*WD;
  const float* bdb = bd + (size_t)bb*NC*HD*WD;
  for (int k = t; k < 1152; k += 256) {
    int c = k / 9, r = k % 9;
    int y = ihp + r/3 - 1, x = iwp + (r % 3) - 1;
    fpat[k] = (((unsigned)y < 64u) && ((unsigned)x < 64u)) ? fdb[(c*HD + y)*WD + x] : 0.f;
  }
  __syncthreads();
  float thr = fdec(rowmax[p]) - CUTS;   // NaN if no unmasked col
  const unsigned short* row = Sb + (size_t)p * NL;
  const float* mb = mmv + bb * NL;
  int l0 = t * 16;
  uint4 q0 = *(const uint4*)(row + l0);
  uint4 q1 = *(const uint4*)(row + l0 + 8);
  unsigned qq[8] = {q0.x,q0.y,q0.z,q0.w,q1.x,q1.y,q1.z,q1.w};
  #pragma unroll
  for (int h = 0; h < 8; ++h) {
    float v0 = bf2f((unsigned short)(qq[h] & 0xffffu));
    float v1 = bf2f((unsigned short)(qq[h] >> 16));
    int c0 = l0 + 2*h, c1 = l0 + 2*h + 1;
    if (mb[c0] != 0.f && v0 >= thr) {
      int slot = atomicAdd(&cnt_s, 1);
      if (slot < MAXC) cl[slot] = c0;
    }
    if (mb[c1] != 0.f && v1 >= thr) {
      int slot = atomicAdd(&cnt_s, 1);
      if (slot < MAXC) cl[slot] = c1;
    }
  }
  __syncthreads();
  int nc = cnt_s < MAXC ? cnt_s : MAXC;
  if (t == 0 && nc > 1) {        // deterministic order: sort candidates by l
    for (int a = 1; a < nc; ++a) {
      int v = cl[a]; int q = a - 1;
      while (q >= 0 && cl[q] > v) { cl[q+1] = cl[q]; --q; }
      cl[q+1] = v;
    }
  }
  __syncthreads();
  for (int a = wid; a < nc; a += 4) {
    int lidx = cl[a]; int ph = lidx >> 6, pw = lidx & 63;
    float sum = 0.f;
    #pragma unroll
    for (int kk = 0; kk < 18; ++kk) {     // 1152 = 18*64
      int k = kk*64 + lane;
      int c = k / 9, r = k % 9;
      int y = ph + r/3 - 1, x = pw + (r % 3) - 1;
      float bv = (((unsigned)y < 64u) && ((unsigned)x < 64u)) ? bdb[(c*HD + y)*WD + x] : 0.f;
      sum = fmaf(fpat[k], bv, sum);
    }
    #pragma unroll
    for (int o = 32; o > 0; o >>= 1) sum += __shfl_xor(sum, o, 64);
    if (lane == 0) cs[a] = sum / fmaxf(nrm[bb*NL + lidx], 1e-4f);
  }
  __syncthreads();
  if (t == 0) {
    float smax = -3e38f; int sidx = 0x7fffffff;
    for (int a = 0; a < nc; ++a)
      if (cs[a] > smax) { smax = cs[a]; sidx = cl[a]; }   // sorted by l
    int Z = zb[bb];
    size_t base = (size_t)(bb*NL + p) * MAXENT;
    if (nc == 0) {
      cnt[bb*NL + p] = 0;
      ooff[((bb*2 + 0)*HD + ihp)*WD + iwp] = (float)(0 - ihp);
      ooff[((bb*2 + 1)*HD + ihp)*WD + iwp] = (float)(0 - iwp);
    } else {
      float xm = smax * SM_SCALE;
      if (Z > 0) xm = fmaxf(xm, 0.f);
      float den = 0.f;
      for (int a = 0; a < nc; ++a) {
        float d = cs[a] * SM_SCALE - xm;
        if (d > -CUT) den += expf(d);
      }
      if (Z > 0 && -xm > -CUT) den += (float)Z * expf(-xm);
      int n = 0;
      for (int a = 0; a < nc && n < MAXENT; ++a) {
        float d = cs[a] * SM_SCALE - xm;
        if (d > -CUT) { ent[base + n].l = cl[a]; ent[base + n].p = expf(d) / den; ++n; }
      }
      cnt[bb*NL + p] = n;
      ooff[((bb*2 + 0)*HD + ihp)*WD + iwp] = (float)((sidx >> 6) - ihp);
      ooff[((bb*2 + 1)*HD + ihp)*WD + iwp] = (float)((sidx & 63) - iwp);
    }
  }
}

// ---------- plan: per output pixel, channel-independent contribution list ----------
__global__ void k_plan(const int* __restrict__ cnt, const Ent* __restrict__ ent,
                       int* __restrict__ npl, int* __restrict__ offs,
                       float* __restrict__ wts) {
  int i = blockIdx.x * blockDim.x + threadIdx.x;
  if (i >= NB*NPIX) return;
  int pix = i & (NPIX-1); int bb = i >> 14;
  int oh = pix >> 7, ow = pix & 127;
  int ihlo = (oh - 1) >> 1;
  int iwlo = (ow - 1) >> 1;
  int n = 0;
  #pragma unroll
  for (int a = 0; a < 2; ++a) {
    int ih = ihlo + a;
    if ((unsigned)ih >= 64u) continue;
    #pragma unroll
    for (int d = 0; d < 2; ++d) {
      int iw = iwlo + d;
      if ((unsigned)iw >= 64u) continue;
      int pidx = bb*NL + ih*WD + iw;
      int nn = cnt[pidx];
      const Ent* ep = ent + (size_t)pidx*MAXENT;
      for (int j = 0; j < nn; ++j) {
        Ent e = ep[j];
        int ph = e.l >> 6, pw = e.l & 63;
        int yy = oh + 2*(ph - ih);
        int xx = ow + 2*(pw - iw);
        if ((unsigned)yy < 128u && (unsigned)xx < 128u) {
          offs[((size_t)bb*PLMAX + n)*NPIX + pix] = yy*NW + xx;
          wts[((size_t)bb*PLMAX + n)*NPIX + pix] = e.p;
          ++n;
        }
      }
    }
  }
  npl[i] = n;
}

// ---------- gather v4: thread = (pixel, channel-quad), pixel-major bt ----------
__global__ __launch_bounds__(256) void k_gather4(const float* __restrict__ bt,
    const int* __restrict__ npl, const int* __restrict__ offs,
    const float* __restrict__ wts, float* __restrict__ yout) {
  __shared__ float sm[8][132];
  int bb = blockIdx.y;
  int pixbase = blockIdx.x * 8;
  int t = threadIdx.x;
  int g = t & 31, pl = t >> 5;
  int c0 = g * 4;
  int pix = pixbase + pl;
  const float* btb = bt + (size_t)bb*NPIX*NC;
  int n = npl[bb*NPIX + pix];
  float ax = 0.f, ay = 0.f, az = 0.f, aw = 0.f;
  for (int j = 0; j < n; ++j) {
    int off = offs[((size_t)bb*PLMAX + j)*NPIX + pix];
    float wv = wts[((size_t)bb*PLMAX + j)*NPIX + pix];
    float4 v = *(const float4*)(btb + (size_t)off*NC + c0);
    ax = fmaf(wv, v.x, ax); ay = fmaf(wv, v.y, ay);
    az = fmaf(wv, v.z, az); aw = fmaf(wv, v.w, aw);
  }
  sm[pl][c0+0] = ax; sm[pl][c0+1] = ay; sm[pl][c0+2] = az; sm[pl][c0+3] = aw;
  __syncthreads();
  #pragma unroll
  for (int k = 0; k < 4; ++k) {
    int c = (t >> 3) + 32*k;
    int i = t & 7;
    yout[((size_t)bb*NC + c)*NPIX + pixbase + i] = sm[i][c] * 0.25f;
  }
}

extern "C" void kernel_launch(void* const* d_in, const int* in_sizes, int n_in,
                              void* d_out, int out_size, void* d_ws, size_t ws_size,
                              hipStream_t stream) {
  const float* f = (const float*)d_in[0];
  const float* b = (const float*)d_in[1];
  const float* mask = (const float*)d_in[2];
  float* out = (float*)d_out;

  char* w = (char*)d_ws;
  float* fd   = (float*)w;  w += (size_t)NB*NC*HD*WD*4;
  float* bd   = (float*)w;  w += (size_t)NB*NC*HD*WD*4;
  double* sq  = (double*)w; w += (size_t)NB*HD*WD*8;
  float* norm = (float*)w;  w += (size_t)NB*NL*4;
  float* mmv  = (float*)w;  w += (size_t)NB*NL*4;
  int* cnt    = (int*)w;    w += (size_t)NB*NL*4;
  Ent* ent    = (Ent*)w;    w += (size_t)NB*NL*MAXENT*sizeof(Ent);
  unsigned short* fdt = (unsigned short*)w; w += (size_t)NB*NL*NC*2;
  unsigned short* bdt = (unsigned short*)w; w += (size_t)NB*NL*NC*2;
  int* zb     = (int*)w;    w += 64;
  unsigned* rowmax = (unsigned*)w; w += (size_t)NL*4;
  int* npl    = (int*)w;    w += (size_t)NB*NPIX*4;
  int* offs   = (int*)w;    w += (size_t)NB*PLMAX*NPIX*4;
  float* wts  = (float*)w;  w += (size_t)NB*PLMAX*NPIX*4;
  // bt (33.5 MB) and Sb (32 MB) alias: Sb used in batch loop, bt only after
  float* bt   = (float*)w;
  unsigned short* Sb = (unsigned short*)w; w += (size_t)NB*NPIX*NC*4;
  unsigned short* D = (unsigned short*)w;   // 32 MB, reused per batch

  int n1 = NB*NC*HD*WD;
  k_prep<<<(n1+255)/256, 256, 0, stream>>>(f, b, fd, bd);
  k_sq<<<(NB*HD*WD+255)/256, 256, 0, stream>>>(bd, sq);
  hipMemsetAsync(zb, 0, 64, stream);
  k_normmm<<<(NB*NL+255)/256, 256, 0, stream>>>(sq, mask, norm, mmv, zb);
  k_fbtrans<<<dim3(NL/32, NC/32, NB), 256, 0, stream>>>(fd, bd, fdt, bdt);

  float* ooff = out + (size_t)NB*NC*NH*NW;
  for (int bb = 0; bb < NB; ++bb) {
    hipMemsetAsync(rowmax, 0, (size_t)NL*4, stream);
    k_gemmD<<<dim3(32, 32), 256, 0, stream>>>(fdt + (size_t)bb*NL*NC,
                                              bdt + (size_t)bb*NL*NC, D);
    k_stencil2<<<NL, 256, 0, stream>>>(D, norm, mmv, Sb, rowmax, bb);
    k_rescore2<<<NL, 256, 0, stream>>>(Sb, mmv, rowmax, fd, bd, norm, zb, cnt, ent, ooff, bb);
  }
  k_btrans<<<dim3(NPIX/32, NC/32, NB), 256, 0, stream>>>(b, bt);
  k_plan<<<(NB*NPIX+255)/256, 256, 0, stream>>>(cnt, ent, npl, offs, wts);
  k_gather4<<<dim3(NPIX/8, NB), 256, 0, stream>>>(bt, npl, offs, wts, out);
}

// Round 8
// 404.711 us; speedup vs baseline: 1.6845x; 1.6845x over previous
//
#include <hip/hip_runtime.h>
#include <cmath>

#define NB 4
#define NC 128
#define NH 128
#define NW 128
#define HD 64
#define WD 64
#define NL 4096      // 64*64 positions / patches
#define NPIX 16384   // 128*128 output pixels per batch
#define SM_SCALE 2550.0f
#define CUT 40.0f
#define CUTS 0.216f  // candidate margin in score units
#define MAXENT 8
#define MAXC 256
#define PLMAX 32     // 4 positions x MAXENT survivors

struct Ent { int l; float p; };

typedef __attribute__((ext_vector_type(4))) float f32x4;
typedef __attribute__((ext_vector_type(8))) short s16x8;

__device__ __forceinline__ unsigned short f2bf(float x) {
  unsigned u = __float_as_uint(x);
  return (unsigned short)((u + 0x7fffu + ((u >> 16) & 1u)) >> 16);
}
__device__ __forceinline__ float bf2f(unsigned short h) {
  return __uint_as_float(((unsigned)h) << 16);
}
__device__ __forceinline__ void gload_lds16(const void* g, void* l) {
  __builtin_amdgcn_global_load_lds(
      (const __attribute__((address_space(1))) void*)g,
      (__attribute__((address_space(3))) void*)l, 16, 0, 0);
}

// ---------- prep ----------
__global__ void k_prep(const float* __restrict__ f, const float* __restrict__ b,
                       float* __restrict__ fd, float* __restrict__ bd) {
  int i = blockIdx.x * blockDim.x + threadIdx.x;
  if (i >= NB*NC*HD*WD) return;
  int x = i & 63, y = (i >> 6) & 63, c = (i >> 12) & 127, bb = i >> 19;
  int src = ((bb*NC + c)*NH + 2*y)*NW + 2*x;
  fd[i] = f[src];
  bd[i] = b[src];
}

__global__ void k_sq(const float* __restrict__ bd, double* __restrict__ sq) {
  int i = blockIdx.x * blockDim.x + threadIdx.x;
  if (i >= NB*HD*WD) return;
  int x = i & 63, y = (i >> 6) & 63, bb = i >> 12;
  double s = 0.0;
  const float* p = bd + (size_t)bb*NC*HD*WD + y*WD + x;
  for (int c = 0; c < NC; ++c) {
    double v = (double)p[(size_t)c*HD*WD];
    s += v*v;
  }
  sq[i] = s;
}

__global__ void k_normmm(const double* __restrict__ sq, const float* __restrict__ mask,
                         float* __restrict__ norm, float* __restrict__ mmv,
                         int* __restrict__ zb) {
  int i = blockIdx.x * blockDim.x + threadIdx.x;
  if (i >= NB*NL) return;
  int pw = i & 63, ph = (i >> 6) & 63, bb = i >> 12;
  double s = 0.0;
  for (int dh = -1; dh <= 1; ++dh) {
    int y = ph + dh; if ((unsigned)y >= 64u) continue;
    for (int dw = -1; dw <= 1; ++dw) {
      int x = pw + dw; if ((unsigned)x >= 64u) continue;
      s += sq[(bb*HD + y)*WD + x];
    }
  }
  norm[i] = (float)sqrt(s);
  float ms = 0.f;
  const float* mb = mask + (size_t)bb*512*512;
  for (int dh = -1; dh <= 1; ++dh) {
    int y = ph + dh; if ((unsigned)y >= 64u) continue;
    for (int dw = -1; dw <= 1; ++dw) {
      int x = pw + dw; if ((unsigned)x >= 64u) continue;
      ms += mb[(y*8)*512 + x*8];
    }
  }
  float m = (ms == 0.f) ? 1.f : 0.f;
  mmv[i] = m;
  if (m == 0.f) atomicAdd(&zb[bb], 1);
}

// ---------- transpose b to pixel-major b_t[bb][pix][c] (for gather) ----------
__global__ __launch_bounds__(256) void k_btrans(const float* __restrict__ b,
                                                float* __restrict__ bt) {
  __shared__ float tile[32][33];
  int bb = blockIdx.z;
  int c0 = blockIdx.y * 32;
  int p0 = blockIdx.x * 32;
  int tx = threadIdx.x & 31, ty = threadIdx.x >> 5;
  const float* bp = b + (size_t)bb*NC*NPIX;
  #pragma unroll
  for (int r = 0; r < 32; r += 8)
    tile[r + ty][tx] = bp[(size_t)(c0 + r + ty)*NPIX + p0 + tx];
  __syncthreads();
  float* btp = bt + (size_t)bb*NPIX*NC;
  #pragma unroll
  for (int r = 0; r < 32; r += 8)
    btp[(size_t)(p0 + r + ty)*NC + c0 + tx] = tile[tx][r + ty];
}

// ---------- transpose fd,bd to pixel-major bf16 (GEMM-D operands) ----------
__global__ __launch_bounds__(256) void k_fbtrans(const float* __restrict__ fd,
    const float* __restrict__ bd, unsigned short* __restrict__ fdt,
    unsigned short* __restrict__ bdt) {
  __shared__ float tf[32][33], tb[32][33];
  int bb = blockIdx.z;
  int c0 = blockIdx.y * 32;
  int p0 = blockIdx.x * 32;
  int tx = threadIdx.x & 31, ty = threadIdx.x >> 5;
  const float* fp = fd + (size_t)bb*NC*NL;
  const float* bp = bd + (size_t)bb*NC*NL;
  #pragma unroll
  for (int r = 0; r < 32; r += 8) {
    tf[r + ty][tx] = fp[(size_t)(c0 + r + ty)*NL + p0 + tx];
    tb[r + ty][tx] = bp[(size_t)(c0 + r + ty)*NL + p0 + tx];
  }
  __syncthreads();
  #pragma unroll
  for (int r = 0; r < 32; r += 8) {
    fdt[((size_t)bb*NL + p0 + r + ty)*NC + c0 + tx] = f2bf(tf[tx][r + ty]);
    bdt[((size_t)bb*NL + p0 + r + ty)*NC + c0 + tx] = f2bf(tb[tx][r + ty]);
  }
}

// ---------- pixel-dot GEMM: D[p][l] = bf16(<fd_pix(p), bd_pix(l)>), K=128 ----------
__global__ __launch_bounds__(256) void k_gemmD(
    const unsigned short* __restrict__ A, const unsigned short* __restrict__ B,
    unsigned short* __restrict__ D) {
  __shared__ __align__(16) unsigned short As[128*32];
  __shared__ __align__(16) unsigned short Bs[128*32];
  int t = threadIdx.x;
  int w = t >> 6, l = t & 63;
  int by = blockIdx.y, bx = blockIdx.x;
  int wr = w >> 1, wc = w & 1;
  f32x4 acc[4][4] = {};
  int aoff[4], boff[4];
  #pragma unroll
  for (int m = 0; m < 4; ++m) {
    aoff[m] = ((wr*64 + m*16 + (l & 15)) * 32 + ((l >> 4) * 8)) * 2;
    boff[m] = ((wc*64 + m*16 + (l & 15)) * 32 + ((l >> 4) * 8)) * 2;
  }
  const char* Ab = (const char*)A;
  const char* Bb = (const char*)B;
  char* AsB = (char*)As;
  char* BsB = (char*)Bs;
  int off = (w*2) * 1024 + l * 16;
  int r0 = off >> 6, cb0 = off & 63;
  int off1 = off + 1024;
  int r1 = off1 >> 6, cb1 = off1 & 63;
  for (int k0 = 0; k0 < 128; k0 += 32) {
    gload_lds16(Ab + ((size_t)(by*128 + r0) * 128 + k0) * 2 + cb0, AsB + (w*2+0)*1024);
    gload_lds16(Ab + ((size_t)(by*128 + r1) * 128 + k0) * 2 + cb1, AsB + (w*2+1)*1024);
    gload_lds16(Bb + ((size_t)(bx*128 + r0) * 128 + k0) * 2 + cb0, BsB + (w*2+0)*1024);
    gload_lds16(Bb + ((size_t)(bx*128 + r1) * 128 + k0) * 2 + cb1, BsB + (w*2+1)*1024);
    __syncthreads();
    s16x8 af[4], bf[4];
    #pragma unroll
    for (int m = 0; m < 4; ++m) af[m] = *(const s16x8*)(AsB + aoff[m]);
    #pragma unroll
    for (int n = 0; n < 4; ++n) bf[n] = *(const s16x8*)(BsB + boff[n]);
    #pragma unroll
    for (int m = 0; m < 4; ++m)
      #pragma unroll
      for (int n = 0; n < 4; ++n)
        acc[m][n] = __builtin_amdgcn_mfma_f32_16x16x32_bf16(af[m], bf[n], acc[m][n], 0, 0, 0);
    __syncthreads();
  }
  int cr = l >> 4;
  int cc = l & 15;
  #pragma unroll
  for (int n = 0; n < 4; ++n) {
    int col = bx*128 + wc*64 + n*16 + cc;
    #pragma unroll
    for (int m = 0; m < 4; ++m) {
      int grow = by*128 + wr*64 + m*16 + cr*4;
      #pragma unroll
      for (int j = 0; j < 4; ++j)
        D[(size_t)(grow + j) * NL + col] = f2bf(acc[m][n][j]);
    }
  }
}

// ---------- horizontal pass: E[p][l] = sum_dw D[p+dw][l+dw], register-shifted ----------
__global__ __launch_bounds__(256) void k_hpass(const unsigned short* __restrict__ D,
                                               unsigned short* __restrict__ E) {
  int p = blockIdx.x;
  int px = p & 63;
  int t = threadIdx.x;
  bool okm = px > 0, okp = px < 63;
  const unsigned short* r0 = D + (size_t)p*NL;
  const unsigned short* rm = D + (size_t)(okm ? p-1 : p)*NL;
  const unsigned short* rp = D + (size_t)(okp ? p+1 : p)*NL;
  #pragma unroll
  for (int ch = 0; ch < 2; ++ch) {
    int l0 = (ch*256 + t) * 8;
    uint4 b0 = *(const uint4*)(r0 + l0);
    int lam = l0 ? (l0 - 8) : 0;
    uint4 am = *(const uint4*)(rm + lam);
    uint4 bm = *(const uint4*)(rm + l0);
    uint4 bp = *(const uint4*)(rp + l0);
    int lcp = (l0 < NL - 8) ? (l0 + 8) : l0;
    uint4 cp = *(const uint4*)(rp + lcp);
    unsigned bmu[4] = {bm.x, bm.y, bm.z, bm.w};
    unsigned bpu[4] = {bp.x, bp.y, bp.z, bp.w};
    unsigned b0u[4] = {b0.x, b0.y, b0.z, b0.w};
    unsigned sm[4], sp[4];
    sm[0] = (am.w >> 16) | (bmu[0] << 16);
    sm[1] = (bmu[0] >> 16) | (bmu[1] << 16);
    sm[2] = (bmu[1] >> 16) | (bmu[2] << 16);
    sm[3] = (bmu[2] >> 16) | (bmu[3] << 16);
    sp[0] = (bpu[0] >> 16) | (bpu[1] << 16);
    sp[1] = (bpu[1] >> 16) | (bpu[2] << 16);
    sp[2] = (bpu[2] >> 16) | (bpu[3] << 16);
    sp[3] = (bpu[3] >> 16) | (cp.x << 16);
    unsigned eo[4];
    #pragma unroll
    for (int k = 0; k < 4; ++k) {
      int j0 = 2*k;
      int lx0 = (l0 + j0) & 63;
      float v0 = (okm && lx0 > 0) ? bf2f((unsigned short)(sm[k] & 0xffffu)) : 0.f;
      v0 += bf2f((unsigned short)(b0u[k] & 0xffffu));
      v0 += (okp && lx0 < 63) ? bf2f((unsigned short)(sp[k] & 0xffffu)) : 0.f;
      int lx1 = (l0 + j0 + 1) & 63;
      float v1 = (okm && lx1 > 0) ? bf2f((unsigned short)(sm[k] >> 16)) : 0.f;
      v1 += bf2f((unsigned short)(b0u[k] >> 16));
      v1 += (okp && lx1 < 63) ? bf2f((unsigned short)(sp[k] >> 16)) : 0.f;
      eo[k] = (unsigned)f2bf(v0) | ((unsigned)f2bf(v1) << 16);
    }
    uint4 outv; outv.x = eo[0]; outv.y = eo[1]; outv.z = eo[2]; outv.w = eo[3];
    *(uint4*)(E + (size_t)p*NL + l0) = outv;
  }
}

// ---------- fused vertical stencil + rowmax + scan + exact rescore ----------
__global__ __launch_bounds__(256) void k_rescore3(const unsigned short* __restrict__ E,
    const float* __restrict__ mmv, const float* __restrict__ fd,
    const float* __restrict__ bd, const float* __restrict__ nrm,
    const int* __restrict__ zb, int* __restrict__ cnt, Ent* __restrict__ ent,
    float* __restrict__ ooff, int bb) {
  int p = blockIdx.x, t = threadIdx.x;
  int wid = t >> 6, lane = t & 63;
  int ihp = p >> 6, iwp = p & 63;
  int py = p >> 6;
  __shared__ float fpat[1152];
  __shared__ int cl[MAXC];
  __shared__ float cs[MAXC];
  __shared__ float rmx[256];
  __shared__ int cnt_s;
  if (t == 0) cnt_s = 0;
  const float* fdb = fd + (size_t)bb*NC*HD*WD;
  const float* bdb = bd + (size_t)bb*NC*HD*WD;
  for (int k = t; k < 1152; k += 256) {
    int c = k / 9, r = k % 9;
    int y = ihp + r/3 - 1, x = iwp + (r % 3) - 1;
    fpat[k] = (((unsigned)y < 64u) && ((unsigned)x < 64u)) ? fdb[(c*HD + y)*WD + x] : 0.f;
  }

  // vertical 3-tap over E: s[i] for l = t*16 + i
  float sv[16], mv[16];
  const float* mb = mmv + bb*NL;
  #pragma unroll
  for (int ch = 0; ch < 2; ++ch) {
    int l0 = t*16 + ch*8;
    int ly = l0 >> 6;
    bool okm = (py > 0) && (ly > 0);
    bool okp = (py < 63) && (ly < 63);
    size_t a0 = (size_t)p*NL + l0;
    size_t am = okm ? ((size_t)(p-64)*NL + (l0-64)) : a0;
    size_t ap = okp ? ((size_t)(p+64)*NL + (l0+64)) : a0;
    uint4 e0 = *(const uint4*)(E + a0);
    uint4 em = *(const uint4*)(E + am);
    uint4 ep = *(const uint4*)(E + ap);
    unsigned e0u[4] = {e0.x,e0.y,e0.z,e0.w};
    unsigned emu[4] = {em.x,em.y,em.z,em.w};
    unsigned epu[4] = {ep.x,ep.y,ep.z,ep.w};
    #pragma unroll
    for (int k = 0; k < 4; ++k) {
      float v0 = okm ? bf2f((unsigned short)(emu[k] & 0xffffu)) : 0.f;
      v0 += bf2f((unsigned short)(e0u[k] & 0xffffu));
      v0 += okp ? bf2f((unsigned short)(epu[k] & 0xffffu)) : 0.f;
      float v1 = okm ? bf2f((unsigned short)(emu[k] >> 16)) : 0.f;
      v1 += bf2f((unsigned short)(e0u[k] >> 16));
      v1 += okp ? bf2f((unsigned short)(epu[k] >> 16)) : 0.f;
      int i0 = ch*8 + 2*k;
      int l = l0 + 2*k;
      float rn0 = 1.f / fmaxf(nrm[bb*NL + l], 1e-4f);
      float rn1 = 1.f / fmaxf(nrm[bb*NL + l + 1], 1e-4f);
      sv[i0]   = v0 * rn0;
      sv[i0+1] = v1 * rn1;
      mv[i0]   = mb[l];
      mv[i0+1] = mb[l + 1];
    }
  }
  float mx = -3e38f;
  #pragma unroll
  for (int i = 0; i < 16; ++i)
    if (mv[i] != 0.f) mx = fmaxf(mx, sv[i]);
  rmx[t] = mx;
  __syncthreads();
  for (int o = 128; o > 0; o >>= 1) {
    if (t < o) rmx[t] = fmaxf(rmx[t], rmx[t+o]);
    __syncthreads();
  }
  float thr = rmx[0] - CUTS;
  #pragma unroll
  for (int i = 0; i < 16; ++i) {
    if (mv[i] != 0.f && sv[i] >= thr) {
      int slot = atomicAdd(&cnt_s, 1);
      if (slot < MAXC) cl[slot] = t*16 + i;
    }
  }
  __syncthreads();
  int nc = cnt_s < MAXC ? cnt_s : MAXC;
  if (t == 0 && nc > 1) {        // deterministic order: sort candidates by l
    for (int a = 1; a < nc; ++a) {
      int v = cl[a]; int q = a - 1;
      while (q >= 0 && cl[q] > v) { cl[q+1] = cl[q]; --q; }
      cl[q+1] = v;
    }
  }
  __syncthreads();
  for (int a = wid; a < nc; a += 4) {
    int lidx = cl[a]; int ph = lidx >> 6, pw = lidx & 63;
    float sum = 0.f;
    #pragma unroll
    for (int kk = 0; kk < 18; ++kk) {     // 1152 = 18*64
      int k = kk*64 + lane;
      int c = k / 9, r = k % 9;
      int y = ph + r/3 - 1, x = pw + (r % 3) - 1;
      float bv = (((unsigned)y < 64u) && ((unsigned)x < 64u)) ? bdb[(c*HD + y)*WD + x] : 0.f;
      sum = fmaf(fpat[k], bv, sum);
    }
    #pragma unroll
    for (int o = 32; o > 0; o >>= 1) sum += __shfl_xor(sum, o, 64);
    if (lane == 0) cs[a] = sum / fmaxf(nrm[bb*NL + lidx], 1e-4f);
  }
  __syncthreads();
  if (t == 0) {
    float smax = -3e38f; int sidx = 0x7fffffff;
    for (int a = 0; a < nc; ++a)
      if (cs[a] > smax) { smax = cs[a]; sidx = cl[a]; }   // sorted by l
    int Z = zb[bb];
    size_t base = (size_t)(bb*NL + p) * MAXENT;
    if (nc == 0) {
      cnt[bb*NL + p] = 0;
      ooff[((bb*2 + 0)*HD + ihp)*WD + iwp] = (float)(0 - ihp);
      ooff[((bb*2 + 1)*HD + ihp)*WD + iwp] = (float)(0 - iwp);
    } else {
      float xm = smax * SM_SCALE;
      if (Z > 0) xm = fmaxf(xm, 0.f);
      float den = 0.f;
      for (int a = 0; a < nc; ++a) {
        float d = cs[a] * SM_SCALE - xm;
        if (d > -CUT) den += expf(d);
      }
      if (Z > 0 && -xm > -CUT) den += (float)Z * expf(-xm);
      int n = 0;
      for (int a = 0; a < nc && n < MAXENT; ++a) {
        float d = cs[a] * SM_SCALE - xm;
        if (d > -CUT) { ent[base + n].l = cl[a]; ent[base + n].p = expf(d) / den; ++n; }
      }
      cnt[bb*NL + p] = n;
      ooff[((bb*2 + 0)*HD + ihp)*WD + iwp] = (float)((sidx >> 6) - ihp);
      ooff[((bb*2 + 1)*HD + ihp)*WD + iwp] = (float)((sidx & 63) - iwp);
    }
  }
}

// ---------- plan: per output pixel, channel-independent contribution list ----------
__global__ void k_plan(const int* __restrict__ cnt, const Ent* __restrict__ ent,
                       int* __restrict__ npl, int* __restrict__ offs,
                       float* __restrict__ wts) {
  int i = blockIdx.x * blockDim.x + threadIdx.x;
  if (i >= NB*NPIX) return;
  int pix = i & (NPIX-1); int bb = i >> 14;
  int oh = pix >> 7, ow = pix & 127;
  int ihlo = (oh - 1) >> 1;
  int iwlo = (ow - 1) >> 1;
  int n = 0;
  #pragma unroll
  for (int a = 0; a < 2; ++a) {
    int ih = ihlo + a;
    if ((unsigned)ih >= 64u) continue;
    #pragma unroll
    for (int d = 0; d < 2; ++d) {
      int iw = iwlo + d;
      if ((unsigned)iw >= 64u) continue;
      int pidx = bb*NL + ih*WD + iw;
      int nn = cnt[pidx];
      const Ent* ep = ent + (size_t)pidx*MAXENT;
      for (int j = 0; j < nn; ++j) {
        Ent e = ep[j];
        int ph = e.l >> 6, pw = e.l & 63;
        int yy = oh + 2*(ph - ih);
        int xx = ow + 2*(pw - iw);
        if ((unsigned)yy < 128u && (unsigned)xx < 128u) {
          offs[((size_t)bb*PLMAX + n)*NPIX + pix] = yy*NW + xx;
          wts[((size_t)bb*PLMAX + n)*NPIX + pix] = e.p;
          ++n;
        }
      }
    }
  }
  npl[i] = n;
}

// ---------- gather v4: thread = (pixel, channel-quad), pixel-major bt ----------
__global__ __launch_bounds__(256) void k_gather4(const float* __restrict__ bt,
    const int* __restrict__ npl, const int* __restrict__ offs,
    const float* __restrict__ wts, float* __restrict__ yout) {
  __shared__ float sm[8][132];
  int bb = blockIdx.y;
  int pixbase = blockIdx.x * 8;
  int t = threadIdx.x;
  int g = t & 31, pl = t >> 5;
  int c0 = g * 4;
  int pix = pixbase + pl;
  const float* btb = bt + (size_t)bb*NPIX*NC;
  int n = npl[bb*NPIX + pix];
  float ax = 0.f, ay = 0.f, az = 0.f, aw = 0.f;
  for (int j = 0; j < n; ++j) {
    int off = offs[((size_t)bb*PLMAX + j)*NPIX + pix];
    float wv = wts[((size_t)bb*PLMAX + j)*NPIX + pix];
    float4 v = *(const float4*)(btb + (size_t)off*NC + c0);
    ax = fmaf(wv, v.x, ax); ay = fmaf(wv, v.y, ay);
    az = fmaf(wv, v.z, az); aw = fmaf(wv, v.w, aw);
  }
  sm[pl][c0+0] = ax; sm[pl][c0+1] = ay; sm[pl][c0+2] = az; sm[pl][c0+3] = aw;
  __syncthreads();
  #pragma unroll
  for (int k = 0; k < 4; ++k) {
    int c = (t >> 3) + 32*k;
    int i = t & 7;
    yout[((size_t)bb*NC + c)*NPIX + pixbase + i] = sm[i][c] * 0.25f;
  }
}

extern "C" void kernel_launch(void* const* d_in, const int* in_sizes, int n_in,
                              void* d_out, int out_size, void* d_ws, size_t ws_size,
                              hipStream_t stream) {
  const float* f = (const float*)d_in[0];
  const float* b = (const float*)d_in[1];
  const float* mask = (const float*)d_in[2];
  float* out = (float*)d_out;

  char* w = (char*)d_ws;
  float* fd   = (float*)w;  w += (size_t)NB*NC*HD*WD*4;
  float* bd   = (float*)w;  w += (size_t)NB*NC*HD*WD*4;
  double* sq  = (double*)w; w += (size_t)NB*HD*WD*8;
  float* norm = (float*)w;  w += (size_t)NB*NL*4;
  float* mmv  = (float*)w;  w += (size_t)NB*NL*4;
  int* cnt    = (int*)w;    w += (size_t)NB*NL*4;
  Ent* ent    = (Ent*)w;    w += (size_t)NB*NL*MAXENT*sizeof(Ent);
  unsigned short* fdt = (unsigned short*)w; w += (size_t)NB*NL*NC*2;
  unsigned short* bdt = (unsigned short*)w; w += (size_t)NB*NL*NC*2;
  int* zb     = (int*)w;    w += 64;
  int* npl    = (int*)w;    w += (size_t)NB*NPIX*4;
  int* offs   = (int*)w;    w += (size_t)NB*PLMAX*NPIX*4;
  float* wts  = (float*)w;  w += (size_t)NB*PLMAX*NPIX*4;
  // D (32 MB, in-loop) aliases bt (33.5 MB, post-loop)
  float* bt   = (float*)w;
  unsigned short* D = (unsigned short*)w; w += (size_t)NB*NPIX*NC*4;
  unsigned short* E = (unsigned short*)w;   // 32 MB, reused per batch

  int n1 = NB*NC*HD*WD;
  k_prep<<<(n1+255)/256, 256, 0, stream>>>(f, b, fd, bd);
  k_sq<<<(NB*HD*WD+255)/256, 256, 0, stream>>>(bd, sq);
  hipMemsetAsync(zb, 0, 64, stream);
  k_normmm<<<(NB*NL+255)/256, 256, 0, stream>>>(sq, mask, norm, mmv, zb);
  k_fbtrans<<<dim3(NL/32, NC/32, NB), 256, 0, stream>>>(fd, bd, fdt, bdt);

  float* ooff = out + (size_t)NB*NC*NH*NW;
  for (int bb = 0; bb < NB; ++bb) {
    k_gemmD<<<dim3(32, 32), 256, 0, stream>>>(fdt + (size_t)bb*NL*NC,
                                              bdt + (size_t)bb*NL*NC, D);
    k_hpass<<<NL, 256, 0, stream>>>(D, E);
    k_rescore3<<<NL, 256, 0, stream>>>(E, mmv, fd, bd, norm, zb, cnt, ent, ooff, bb);
  }
  k_btrans<<<dim3(NPIX/32, NC/32, NB), 256, 0, stream>>>(b, bt);
  k_plan<<<(NB*NPIX+255)/256, 256, 0, stream>>>(cnt, ent, npl, offs, wts);
  k_gather4<<<dim3(NPIX/8, NB), 256, 0, stream>>>(bt, npl, offs, wts, out);
}